// Round 8
// baseline (281.655 us; speedup 1.0000x reference)
//
#include <hip/hip_runtime.h>
#include <hip/hip_bf16.h>

typedef __attribute__((ext_vector_type(8))) __bf16 bf16x8;
typedef __attribute__((ext_vector_type(4))) __bf16 bf16x4;
typedef __attribute__((ext_vector_type(4))) float f32x4;

constexpr int M = 16384;
constexpr int K = 512;
constexpr int BKT = 64;      // K per K-tile
constexpr int NKT = 8;       // K / BKT

__device__ __forceinline__ void async_copy16(const void* gsrc, void* ldst) {
  __builtin_amdgcn_global_load_lds(
      (const __attribute__((address_space(1))) unsigned int*)(gsrc),
      (__attribute__((address_space(3))) unsigned int*)(ldst),
      16, 0, 0);
}

__device__ __forceinline__ float frcp(float x) { return __builtin_amdgcn_rcpf(x); }
__device__ __forceinline__ float ftanh(float x) {
  return 1.0f - 2.0f * frcp(1.0f + __expf(2.0f * x));
}
__device__ __forceinline__ float fsigm(float x) { return frcp(1.0f + __expf(-x)); }

// Epilogue scratch swizzle (R4-proven): row stride bank-aligned; per-row XOR
// on the 8-el chunk gives the 4 kc row-groups (and 4 r values) distinct
// shifts -> stores 2-way max (free), reads sweep each row exactly once.
__device__ __forceinline__ int kswz(int row) {
  return ((row & 3) << 3) ^ ((row & 12) << 2);
}

// Phase sync (rule 18 at every joint)
#define MIDSYNC                                                  \
  __builtin_amdgcn_s_barrier();                                  \
  asm volatile("s_waitcnt lgkmcnt(0)" ::: "memory");             \
  __builtin_amdgcn_sched_barrier(0);
#define ENDSYNC                                                  \
  __builtin_amdgcn_s_barrier();                                  \
  __builtin_amdgcn_sched_barrier(0);

#define QUAD(g, p, AF, BF)                                               \
  _Pragma("unroll") for (int i_ = 0; i_ < 4; ++i_)                       \
  _Pragma("unroll") for (int n_ = 0; n_ < 2; ++n_)                       \
  _Pragma("unroll") for (int kk_ = 0; kk_ < 2; ++kk_)                    \
    acc[(g)*4 + i_][(p)*2 + n_] = __builtin_amdgcn_mfma_f32_16x16x32_bf16( \
        AF[i_][kk_], BF[n_][kk_], acc[(g)*4 + i_][(p)*2 + n_], 0, 0, 0);

// ---------------------------------------------------------------------------
// R8: true pipelined schedule (m201-family), 256x256 tile, BK=64, 8 waves
// (512 thr), wave-tile 128x64. R6/R7 post-mortem: every knob inside the
// 2-phase lockstep lands at ~500 TF (structural stage->drain->barrier
// ceiling); LDS BW at 256 B/clk/CU supports ~60% MfmaUtil at this blocking,
// so the schedule is the only cap.
// Structure per K-tile (4 phases, quadrants Q(g=mi-half, p=ni-pair)):
//   ph0: ldA(g0) 8 + ldB(p0) 4 reads              | MFMA Q00
//   ph1: ldB(p1) 4 reads                          | MFMA Q01
//   ph2: ldA(g1) 8 reads | stage B(t+2)           | MFMA Q10
//   ph3:                 | stage A(t+2)           | MFMA Q11 | vmcnt(8)
// each phase: reads/stage -> s_barrier -> lgkmcnt(0) -> sched_barrier ->
// setprio(1) MFMA setprio(0) -> s_barrier -> sched_barrier.
// WHY THE COUNTED vmcnt IS SOUND (R5's missing piece): staging is
// GROUP-LOCAL - a wave DMA-writes exactly the regions it reads (its A-half:
// waves with same wid&1; its B-half: same wid>>2). Writers == readers per
// region, so each wave's own vmcnt covers every byte it reads. Region
// lifetime: B-reads end ph1 (lgkm0 + end-bar), A-reads end ph2 -> staging
// t+2 (same buffer as t) at ph2/ph3 is write-after-read-safe. Lead = 2
// K-tiles -> steady wait vmcnt(8), never a drain.
// Swizzle: 8-chunk XOR, key = row&7 (= lane>>3 on the DMA source, = fr&7 on
// frag reads; base rows == 0 mod 8). LDS: 2 buf x 64 KB = 128 KB, 1 blk/CU.
// SPILL WATCH: VGPR 128 + WRITE_SIZE >> 50 MB => allocator spilled => revert.
// NOTE: never runtime-index acc[]/frag arrays (R2 scratch lesson) - QUAD has
// literal g,p; all frag loops unrolled.
// ---------------------------------------------------------------------------
template <int MODE>   // 1: a1 = tanh(hx@W1^T+b1); 2: gates = act(a1@W2^T+b2)
__global__ __launch_bounds__(512, 2) void gemm8(
    const __bf16* __restrict__ Ab,   // MODE1: hxb [M][512]; MODE2: a1 planes
    const __bf16* __restrict__ W,    // [3][512][512] bf16 (N,K) row-major
    const float* __restrict__ bias,  // [7][512] fp32
    __bf16* __restrict__ outb)       // [3][M][512] bf16
{
  const int jj = blockIdx.z;
  const int mbase = blockIdx.x * 256;
  const int nbase = blockIdx.y * 256;
  constexpr size_t NH = (size_t)M * 512;
  const __bf16* Aj = (MODE == 1) ? Ab : Ab + (size_t)jj * NH;
  const __bf16* Wj = W + (size_t)jj * 262144;
  const int brow = 2 * jj + 1;     // bias row: i2=1, f2=3, z=5

  // 2 buffers x 64 KB; buffer beta: [A0 16K][A1 16K][B0 16K][B1 16K]
  // (regions 8192 el = 128 rows x 64 el). Epilogue scratch reuses [0..32767].
  __shared__ __align__(16) __bf16 smem[65536];

  const int tid = threadIdx.x, wid = tid >> 6, lane = tid & 63;
  const int a  = wid & 1;            // A-half this wave reads/stages
  const int wn = (wid >> 1) * 64;    // wave N-offset 0/64/128/192
  const int b  = wid >> 2;           // B-half this wave reads/stages
  const int fr = lane & 15, kc = lane >> 4;
  const int rowq = kc * 4;

  // staging: per-wave 4 copies/region-quarter; src chunk pre-swizzled by
  // (row mod 8) = lane>>3 so linear DMA dest + swizzled frag reads agree.
  const int sr8 = lane >> 3;
  const int sch = (lane & 7) ^ sr8;
  const int w1 = wid >> 1;           // A-stage slice (4 waves share A_a)
  const int w2 = wid & 3;            // B-stage slice (4 waves share B_b)
  const __bf16* Asrc =
      Aj + (size_t)(mbase + a * 128 + w1 * 32 + sr8) * K + sch * 8;
  const __bf16* Bsrc =
      Wj + (size_t)(nbase + b * 128 + w2 * 32 + sr8) * K + sch * 8;
  const int AdstB = a * 8192 + w1 * 32 * 64;
  const int BdstB = 16384 + b * 8192 + w2 * 32 * 64;

  auto stageA = [&](int beta, int k0) {
#pragma unroll
    for (int c = 0; c < 4; ++c)
      async_copy16(Asrc + (size_t)(c * 8) * K + k0,
                   (void*)&smem[beta * 32768 + AdstB + c * 512]);
  };
  auto stageB = [&](int beta, int k0) {
#pragma unroll
    for (int c = 0; c < 4; ++c)
      async_copy16(Bsrc + (size_t)(c * 8) * K + k0,
                   (void*)&smem[beta * 32768 + BdstB + c * 512]);
  };

  auto ldA = [&](int beta, int g, bf16x8 (&af)[4][2]) {
#pragma unroll
    for (int i = 0; i < 4; ++i)
#pragma unroll
      for (int kk = 0; kk < 2; ++kk) {
        const int r = (g * 4 + i) * 16 + fr;
        af[i][kk] = *(const bf16x8*)&smem[beta * 32768 + a * 8192 + r * 64 +
                                          (((kk << 2) | kc) ^ (fr & 7)) * 8];
      }
  };
  auto ldB = [&](int beta, int p, bf16x8 (&bf)[2][2]) {
#pragma unroll
    for (int n = 0; n < 2; ++n)
#pragma unroll
      for (int kk = 0; kk < 2; ++kk) {
        const int r = (wn & 64) + (p * 2 + n) * 16 + fr;
        bf[n][kk] = *(const bf16x8*)&smem[beta * 32768 + 16384 + b * 8192 +
                                          r * 64 +
                                          (((kk << 2) | kc) ^ (fr & 7)) * 8];
      }
  };

  f32x4 acc[8][4] = {};

  // prologue: K-tiles 0 and 1 (FIFO: B0,A0,B1,A1 -> vmcnt(8) retires tile 0)
  stageB(0, 0);    stageA(0, 0);
  stageB(1, BKT);  stageA(1, BKT);
  asm volatile("s_waitcnt vmcnt(8)" ::: "memory");
  __builtin_amdgcn_s_barrier();
  __builtin_amdgcn_sched_barrier(0);

  bf16x8 afA[4][2], afB[4][2], bfA[2][2], bfB[2][2];
#pragma unroll 1
  for (int t = 0; t < NKT; ++t) {
    const int beta = t & 1;
    const bool pre = (t + 2 < NKT);
    // phase 0
    ldA(beta, 0, afA);
    ldB(beta, 0, bfA);
    MIDSYNC;
    __builtin_amdgcn_s_setprio(1); QUAD(0, 0, afA, bfA);
    __builtin_amdgcn_s_setprio(0);
    ENDSYNC;
    // phase 1
    ldB(beta, 1, bfB);
    MIDSYNC;
    __builtin_amdgcn_s_setprio(1); QUAD(0, 1, afA, bfB);
    __builtin_amdgcn_s_setprio(0);
    ENDSYNC;
    // phase 2 (B-regions of this buffer dead after phase-1 end barrier)
    ldA(beta, 1, afB);
    if (pre) stageB(beta, (t + 2) * BKT);
    MIDSYNC;
    __builtin_amdgcn_s_setprio(1); QUAD(1, 0, afB, bfA);
    __builtin_amdgcn_s_setprio(0);
    ENDSYNC;
    // phase 3 (A-regions dead after phase-2 end barrier)
    if (pre) stageA(beta, (t + 2) * BKT);
    MIDSYNC;
    __builtin_amdgcn_s_setprio(1); QUAD(1, 1, afB, bfB);
    __builtin_amdgcn_s_setprio(0);
    if (t < NKT - 1) {
      if (pre) asm volatile("s_waitcnt vmcnt(8)" ::: "memory");
      else     asm volatile("s_waitcnt vmcnt(0)" ::: "memory");
    }
    ENDSYNC;
  }

  // Epilogue. C/D layout: col=fr, row=rowq+r. Two row-half passes through
  // kswz'd scratch [128][256] (proven bank math), fully coalesced stores.
  float bv[4];
  const float* bj = bias + (size_t)brow * 512 + nbase + wn;
#pragma unroll
  for (int ni = 0; ni < 4; ++ni) bv[ni] = bj[ni * 16 + fr];

  __syncthreads();
#pragma unroll
  for (int h = 0; h < 2; ++h) {
    if (a == h) {
#pragma unroll
      for (int mi = 0; mi < 8; ++mi)
#pragma unroll
        for (int ni = 0; ni < 4; ++ni)
#pragma unroll
          for (int r = 0; r < 4; ++r) {
            float v = acc[mi][ni][r] + bv[ni];
            float res;
            if constexpr (MODE == 1) res = ftanh(v);
            else res = (jj == 2) ? ftanh(fsigm(ftanh(v)))  // z, stored tanh'd
                                 : fsigm(ftanh(v));        // i2 / f2
            const int row = mi * 16 + rowq + r;            // 0..127
            const int col = wn + ni * 16 + fr;             // 0..255
            smem[row * 256 + (col ^ kswz(row))] = (__bf16)res;
          }
    }
    __syncthreads();
#pragma unroll
    for (int it = 0; it < 8; ++it) {
      const int s = it * 512 + tid;        // 0..4095
      const int row = s >> 5, ch = s & 31;
      bf16x8 v = *(const bf16x8*)&smem[row * 256 + ((ch * 8) ^ kswz(row))];
      *(bf16x8*)&outb[(size_t)jj * NH +
                      (size_t)(mbase + h * 128 + row) * 512 + (nbase + ch * 8)] =
          v;
    }
    __syncthreads();
  }
}

// cy2 = f2*cx2 + i2*z   gates = [i2 | f2 | z(tanh'd)] bf16 [3][M][512]
__global__ __launch_bounds__(256) void final_kernel(
    const __bf16* __restrict__ gates, const float* __restrict__ cx2,
    float* __restrict__ out)
{
  constexpr size_t NH = (size_t)M * 512;
  const size_t i = ((size_t)blockIdx.x * 256 + threadIdx.x) * 8;
  bf16x8 i2 = *(const bf16x8*)&gates[i];
  bf16x8 f2 = *(const bf16x8*)&gates[NH + i];
  bf16x8 zz = *(const bf16x8*)&gates[2 * NH + i];
  f32x4 c0 = *(const f32x4*)&cx2[i];
  f32x4 c1 = *(const f32x4*)&cx2[i + 4];
#pragma unroll
  for (int h = 0; h < 2; ++h) {
    f32x4 r;
#pragma unroll
    for (int q = 0; q < 4; ++q) {
      const int e = h * 4 + q;
      r[q] = (float)f2[e] * (h ? c1[q] : c0[q]) + (float)i2[e] * (float)zz[e];
    }
    *(f32x4*)&out[i + h * 4] = r;
  }
}

// One conversion dispatch: blocks [0,1536) pick rows 2y+1 of W1/W2
// ([7][512][512] fp32) -> Wb [6][512][512] bf16; blocks [1536,9728) convert
// hx [M][512] fp32 -> hxb bf16.
__global__ __launch_bounds__(256) void cvt_all(const float* __restrict__ hx,
                                               const float* __restrict__ W1,
                                               const float* __restrict__ W2,
                                               __bf16* __restrict__ hxb,
                                               __bf16* __restrict__ Wb) {
  const int bk = blockIdx.x;
  if (bk < 1536) {
    const int y = bk >> 8;         // 0..5
    const int bb = bk & 255;
    const float* src = (y < 3) ? W1 + (size_t)(2 * y + 1) * 262144
                               : W2 + (size_t)(2 * (y - 3) + 1) * 262144;
    __bf16* d = Wb + (size_t)y * 262144;
    const size_t i = ((size_t)bb * 256 + threadIdx.x) * 4;
    f32x4 v = *(const f32x4*)&src[i];
    *(bf16x4*)&d[i] = __builtin_convertvector(v, bf16x4);
  } else {
    const size_t i = ((size_t)(bk - 1536) * 256 + threadIdx.x) * 4;
    f32x4 v = *(const f32x4*)&hx[i];
    *(bf16x4*)&hxb[i] = __builtin_convertvector(v, bf16x4);
  }
}

extern "C" void kernel_launch(void* const* d_in, const int* in_sizes, int n_in,
                              void* d_out, int out_size, void* d_ws, size_t ws_size,
                              hipStream_t stream) {
  const float* hx  = (const float*)d_in[0];
  // d_in[1] = cx1 (dead: cy1 is never returned)
  const float* cx2 = (const float*)d_in[2];
  const float* W1  = (const float*)d_in[3];
  const float* b1  = (const float*)d_in[4];
  const float* W2  = (const float*)d_in[5];
  const float* b2  = (const float*)d_in[6];
  float* out = (float*)d_out;

  // ws: Wb @0 (3MB, [6]: 0-2=W1, 3-5=W2) | hxb @3MB (16MB) |
  //     a1 @19922944 (48MB) | gates @70254592 (48MB: i2,f2,z) -> ~118MB
  char* ws = (char*)d_ws;
  __bf16* Wb    = (__bf16*)(ws);
  __bf16* hxb   = (__bf16*)(ws + 3145728);
  __bf16* a1    = (__bf16*)(ws + 19922944);
  __bf16* gates = (__bf16*)(ws + 70254592);
  __bf16* W2b   = Wb + 3 * 262144;

  cvt_all<<<9728, 256, 0, stream>>>(hx, W1, W2, hxb, Wb);

  // layer 1 (3 nets): 64 x 2 x 3 = 384 blocks, 1/CU
  gemm8<1><<<dim3(64, 2, 3), 512, 0, stream>>>(hxb, Wb, b1, a1);
  // layer 2 (3 nets incl z)
  gemm8<2><<<dim3(64, 2, 3), 512, 0, stream>>>(a1, W2b, b2, gates);
  // combine
  final_kernel<<<4096, 256, 0, stream>>>(gates, cx2, out);
}

// Round 9
// 226.832 us; speedup vs baseline: 1.2417x; 1.2417x over previous
//
#include <hip/hip_runtime.h>
#include <hip/hip_bf16.h>

typedef __attribute__((ext_vector_type(8))) __bf16 bf16x8;
typedef __attribute__((ext_vector_type(4))) __bf16 bf16x4;
typedef __attribute__((ext_vector_type(4))) float f32x4;

constexpr int M = 16384;
constexpr int K = 512;
constexpr int BK = 32;
constexpr int NT = 16;       // K / BK

__device__ __forceinline__ void async_copy16(const void* gsrc, void* ldst) {
  __builtin_amdgcn_global_load_lds(
      (const __attribute__((address_space(1))) unsigned int*)(gsrc),
      (__attribute__((address_space(3))) unsigned int*)(ldst),
      16, 0, 0);
}

__device__ __forceinline__ float frcp(float x) { return __builtin_amdgcn_rcpf(x); }
__device__ __forceinline__ float ftanh(float x) {
  return 1.0f - 2.0f * frcp(1.0f + __expf(2.0f * x));
}
__device__ __forceinline__ float fsigm(float x) { return frcp(1.0f + __expf(-x)); }

// Epilogue scratch swizzle (R4-proven): row stride 128 els (256B, bank-
// aligned); per-row XOR on the 8-el chunk gives the 4 kc row-groups distinct
// shifts -> stores 2-way max (free), reads cover each row once.
__device__ __forceinline__ int kswz(int row) {
  return ((row & 3) << 3) ^ ((row & 12) << 2);
}

// ---------------------------------------------------------------------------
// R9 = R6 (best-known, 224.1us) + XCD-chunked block swizzle (T1).
// R8 POST-MORTEM: the 4-phase pipelined schedule did NOT reproduce the m201
// overlap here (82us, MfmaUtil 12%, one 19.5ms outlier) - m232's open
// quadrant. R5-R8 conclusion: on this shape every schedule variant lands at
// or below the simple loop's ~500 TF; the remaining diagnosed bottleneck is
// STAGING LATENCY: A-panels (the 16-48MB re-read stream) are shared by
// GB blocks each, but default round-robin bid->XCD spreads those blocks
// across all 8 XCDs -> A staging comes from L3 (~500-700cy) or HBM (~900cy),
// at/over the pipeline's ~2-step (~700cy) lead.
// FIX: 1-D grid + bijective chunk swizzle wg=(bid&7)*(n/8)+(bid>>3): each
// XCD gets a contiguous logical range = complete per-mtile reuse groups ->
// every A-panel is fetched into exactly ONE XCD's L2 (~200cy, covered);
// whole B set (1.5MB) + ~16 A-panels (2MB) fit the 4MB L2.
// Logical order: wg = mtile*GB + (jj*4 + ny), GB = 12/8/4 for MODE 1/2/3.
// Kernel body, sync structure, epilogues: byte-identical to R6.
// MODES: 1: a1=tanh(hx@W1^T+b1) all 3 nets; 2: gates=sigm(tanh(a1@W2^T+b2))
// j in {0,1}; 3: z-net + combine out = f2*cx2 + i2*z (gates from prior
// dispatch, stream-ordered; coalesced via LDS scratch).
// LDS: 3 x (As 4096 + Bs 4096) el = 48KB -> 3 blocks/CU cap.
// NOTE: never runtime-index acc[]/frag arrays (scratch spill lesson).
// ---------------------------------------------------------------------------
template <int MODE>
__global__ __launch_bounds__(256) void gemm_kernel(
    const __bf16* __restrict__ Ab,     // MODE1: hxb [M][512]; else a1 planes
    const __bf16* __restrict__ W,      // [3][512][512] bf16 (N,K) row-major
    const float* __restrict__ bias,    // [7][512] fp32
    __bf16* __restrict__ outb,         // MODE1: a1 base; MODE2: gates base
    const __bf16* __restrict__ gates,  // MODE3: [2][M][512] bf16 (i2, f2)
    const float* __restrict__ cx2,     // MODE3
    float* __restrict__ outf)          // MODE3: [M][512] fp32
{
  // XCD-chunked bijective swizzle (grid.x % 8 == 0 for all modes).
  const int bid = blockIdx.x;
  const int cpx = gridDim.x >> 3;                  // blocks per XCD chunk
  const int wg  = (bid & 7) * cpx + (bid >> 3);    // logical wg id
  constexpr int GB = (MODE == 1) ? 12 : (MODE == 2) ? 8 : 4;  // wgs per mtile
  const int mtile = wg / GB;
  const int rem   = wg % GB;
  const int ny    = rem & 3;
  const int jj    = (MODE == 3) ? 2 : (rem >> 2);  // net index
  const int mbase = mtile * 128;
  const int nbase = ny * 128;
  constexpr size_t NH = (size_t)M * 512;

  const __bf16* Aj = (MODE == 1) ? Ab : Ab + (size_t)jj * NH;
  const __bf16* Wj = W + (size_t)jj * 262144;
  const int brow = 2 * jj + 1;                // b-row: i2=1, f2=3, z=5

  // 3 staging buffers x 8192 el (16KB each) = 48KB; scratch reuses [0..16383]
  __shared__ __align__(16) __bf16 smem[24576];

  const int tid  = threadIdx.x;
  const int wid  = tid >> 6;
  const int lane = tid & 63;
  const int wm   = (wid >> 1) * 64;
  const int wn   = (wid & 1) * 64;
  const int srow = wid * 16 + (lane >> 2);
  const int scol = ((lane & 3) ^ ((lane >> 3) & 3)) * 8;  // swizzled src chunk
  const int fr   = lane & 15;
  const int kc   = lane >> 4;
  const int sw   = (fr >> 1) & 3;
  const int rowq = kc * 4;

  auto stage = [&](int p, int k0) {
    __bf16* As = smem + p * 8192;
    __bf16* Bs = As + 4096;
#pragma unroll
    for (int r = 0; r < 2; ++r) {
      async_copy16(Aj + (size_t)(mbase + r * 64 + srow) * K + (k0 + scol),
                   (void*)&As[(r * 64 + wid * 16) * BK]);
      async_copy16(Wj + (size_t)(nbase + r * 64 + srow) * K + (k0 + scol),
                   (void*)&Bs[(r * 64 + wid * 16) * BK]);
    }
  };

  f32x4 acc[4][4] = {};

  stage(0, 0);
  stage(1, BK);
  int pr = 0, ps = 2;
  for (int t = 0; t < NT; ++t) {
    // ONE waitcnt: retire this wave's ds_reads (lgkmcnt 0) AND everything
    // but the newest stage (vmcnt 4) BEFORE the barrier. Tile t+2's copies
    // stay in flight across it (never drain to 0 mid-loop).
    if (t < NT - 2) asm volatile("s_waitcnt vmcnt(4) lgkmcnt(0)" ::: "memory");
    else            asm volatile("s_waitcnt vmcnt(0) lgkmcnt(0)" ::: "memory");
    __builtin_amdgcn_s_barrier();
    __builtin_amdgcn_sched_barrier(0);   // rule #18: pin code below the bar
    if (t < NT - 2) stage(ps, (t + 2) * BK);

    const __bf16* As = smem + pr * 8192;
    const __bf16* Bs = As + 4096;
    bf16x8 af[4], bfr[4];
#pragma unroll
    for (int i = 0; i < 4; ++i) {
      af[i]  = *(const bf16x8*)&As[(wm + i * 16 + fr) * BK + ((kc ^ sw) * 8)];
      bfr[i] = *(const bf16x8*)&Bs[(wn + i * 16 + fr) * BK + ((kc ^ sw) * 8)];
    }
#pragma unroll
    for (int mi = 0; mi < 4; ++mi)
#pragma unroll
      for (int ni = 0; ni < 4; ++ni)
        acc[mi][ni] = __builtin_amdgcn_mfma_f32_16x16x32_bf16(
            af[mi], bfr[ni], acc[mi][ni], 0, 0, 0);

    pr = (pr == 2) ? 0 : pr + 1;
    ps = (ps == 2) ? 0 : ps + 1;
  }

  // Epilogue. C/D layout: col=fr, row=rowq+r.
  float bv[4];
  const float* bj = bias + (size_t)brow * 512 + nbase + wn;
#pragma unroll
  for (int ni = 0; ni < 4; ++ni) bv[ni] = bj[ni * 16 + fr];

  __syncthreads();  // full drain once; smem reusable as C scratch
#pragma unroll
  for (int mi = 0; mi < 4; ++mi)
#pragma unroll
    for (int ni = 0; ni < 4; ++ni)
#pragma unroll
      for (int r = 0; r < 4; ++r) {
        float v = acc[mi][ni][r] + bv[ni];
        float res;
        if constexpr (MODE == 1) res = ftanh(v);
        else if constexpr (MODE == 2) res = fsigm(ftanh(v));
        else res = ftanh(fsigm(ftanh(v)));          // z (bf16-rounded below)
        const int row = wm + mi * 16 + rowq + r;
        const int col = wn + ni * 16 + fr;
        smem[row * 128 + (col ^ kswz(row))] = (__bf16)res;
      }
  __syncthreads();

  if constexpr (MODE <= 2) {
#pragma unroll
    for (int it = 0; it < 8; ++it) {
      const int s = it * 256 + tid;   // 0..2047
      const int row = s >> 4, ch = s & 15;
      bf16x8 v = *(const bf16x8*)&smem[row * 128 + ((ch * 8) ^ kswz(row))];
      *(bf16x8*)&outb[(size_t)jj * NH + (size_t)(mbase + row) * 512 +
                      (nbase + ch * 8)] = v;
    }
  } else {
    // coalesced combine: out = f2*cx2 + i2*z (16B/32B contiguous per lane)
#pragma unroll
    for (int it = 0; it < 8; ++it) {
      const int s = it * 256 + tid;
      const int row = s >> 4, ch = s & 15;
      const size_t gidx = (size_t)(mbase + row) * 512 + (nbase + ch * 8);
      bf16x8 zv = *(const bf16x8*)&smem[row * 128 + ((ch * 8) ^ kswz(row))];
      bf16x8 i2 = *(const bf16x8*)&gates[gidx];
      bf16x8 f2 = *(const bf16x8*)&gates[NH + gidx];
      f32x4 c0 = *(const f32x4*)&cx2[gidx];
      f32x4 c1 = *(const f32x4*)&cx2[gidx + 4];
      f32x4 r0, r1;
#pragma unroll
      for (int q = 0; q < 4; ++q) {
        r0[q] = (float)f2[q] * c0[q] + (float)i2[q] * (float)zv[q];
        r1[q] = (float)f2[4 + q] * c1[q] + (float)i2[4 + q] * (float)zv[4 + q];
      }
      *(f32x4*)&outf[gidx] = r0;
      *(f32x4*)&outf[gidx + 4] = r1;
    }
  }
}

// One conversion dispatch: blocks [0,1536) pick rows 2y+1 of W1/W2
// ([7][512][512] fp32) -> Wb [6][512][512] bf16; blocks [1536,9728) convert
// hx [M][512] fp32 -> hxb bf16.
__global__ __launch_bounds__(256) void cvt_all(const float* __restrict__ hx,
                                               const float* __restrict__ W1,
                                               const float* __restrict__ W2,
                                               __bf16* __restrict__ hxb,
                                               __bf16* __restrict__ Wb) {
  const int b = blockIdx.x;
  if (b < 1536) {
    const int y = b >> 8;          // 0..5
    const int bb = b & 255;
    const float* src = (y < 3) ? W1 + (size_t)(2 * y + 1) * 262144
                               : W2 + (size_t)(2 * (y - 3) + 1) * 262144;
    __bf16* d = Wb + (size_t)y * 262144;
    const size_t i = ((size_t)bb * 256 + threadIdx.x) * 4;
    f32x4 v = *(const f32x4*)&src[i];
    *(bf16x4*)&d[i] = __builtin_convertvector(v, bf16x4);
  } else {
    const size_t i = ((size_t)(b - 1536) * 256 + threadIdx.x) * 4;
    f32x4 v = *(const f32x4*)&hx[i];
    *(bf16x4*)&hxb[i] = __builtin_convertvector(v, bf16x4);
  }
}

extern "C" void kernel_launch(void* const* d_in, const int* in_sizes, int n_in,
                              void* d_out, int out_size, void* d_ws, size_t ws_size,
                              hipStream_t stream) {
  const float* hx  = (const float*)d_in[0];
  // d_in[1] = cx1 (dead: cy1 is never returned)
  const float* cx2 = (const float*)d_in[2];
  const float* W1  = (const float*)d_in[3];
  const float* b1  = (const float*)d_in[4];
  const float* W2  = (const float*)d_in[5];
  const float* b2  = (const float*)d_in[6];
  float* out = (float*)d_out;

  // ws: Wb @0 (3MB, [6] planes: 0-2=W1, 3-5=W2) | hxb @3MB (16MB) |
  //     a1 @19922944 (48MB) | gates @70254592 (32MB) -> ~102MB
  char* ws = (char*)d_ws;
  __bf16* Wb    = (__bf16*)(ws);
  __bf16* hxb   = (__bf16*)(ws + 3145728);
  __bf16* a1    = (__bf16*)(ws + 19922944);
  __bf16* gates = (__bf16*)(ws + 70254592);
  __bf16* W2b   = Wb + 3 * 262144;

  cvt_all<<<9728, 256, 0, stream>>>(hx, W1, W2, hxb, Wb);

  // layer 1 (3 nets): 1536 logical wgs = 128 mtiles x (3 nets x 4 ny)
  gemm_kernel<1><<<1536, 256, 0, stream>>>(
      hxb, Wb, b1, a1, nullptr, nullptr, nullptr);
  // layer 2 gates i2, f2: 1024 wgs = 128 x (2 x 4)
  gemm_kernel<2><<<1024, 256, 0, stream>>>(
      a1, W2b, b2, gates, nullptr, nullptr, nullptr);
  // layer 2 z + final combine: 512 wgs = 128 x 4
  gemm_kernel<3><<<512, 256, 0, stream>>>(
      a1, W2b, b2, nullptr, gates, cx2, out);
}

// Round 10
// 222.471 us; speedup vs baseline: 1.2660x; 1.0196x over previous
//
#include <hip/hip_runtime.h>
#include <hip/hip_bf16.h>

typedef __attribute__((ext_vector_type(8))) __bf16 bf16x8;
typedef __attribute__((ext_vector_type(4))) __bf16 bf16x4;
typedef __attribute__((ext_vector_type(4))) float f32x4;

constexpr int M = 16384;
constexpr int K = 512;
constexpr int BK = 32;
constexpr int NT = 16;       // K / BK

__device__ __forceinline__ void async_copy16(const void* gsrc, void* ldst) {
  __builtin_amdgcn_global_load_lds(
      (const __attribute__((address_space(1))) unsigned int*)(gsrc),
      (__attribute__((address_space(3))) unsigned int*)(ldst),
      16, 0, 0);
}

__device__ __forceinline__ float frcp(float x) { return __builtin_amdgcn_rcpf(x); }
__device__ __forceinline__ float ftanh(float x) {
  return 1.0f - 2.0f * frcp(1.0f + __expf(2.0f * x));
}
__device__ __forceinline__ float fsigm(float x) { return frcp(1.0f + __expf(-x)); }

// Epilogue scratch swizzle (R4-proven): row stride 128 els (256B, bank-
// aligned); per-row XOR on the 8-el chunk gives the 4 kc row-groups distinct
// shifts -> stores 2-way max (free), reads cover each row once.
__device__ __forceinline__ int kswz(int row) {
  return ((row & 3) << 3) ^ ((row & 12) << 2);
}

// ---------------------------------------------------------------------------
// R10 = R9 (best MODE1 counters: FETCH halved by XCD chunking, 41us) with
// the DISPATCH PACKING fixed. R9 post-mortem: per-block time ~20.5us is the
// makespan quantum at 768 concurrent slots (3 blk/CU); MODE2's 1024 blocks
// spanned 2 quanta for 1.33 rounds of work (33% idle straggler round) and
// MODE3 added a 2/3-full round + 96MB combine traffic. FIX: layer 2 is ONE
// uniform 1536-block dispatch (all 3 nets, z stored tanh'd - R7-proven
// epilogue) = exactly 2 full rounds; combine moves to R0's proven streaming
// final_kernel (4096 tiny blocks, perfect packing).
// Established this session (R5-R9): 2-phase lockstep plateau ~630 TF at this
// shape; counted vmcnt/geometry/phase-split all null or regress; XCD chunk
// swizzle is real at the counter level (FETCH 31->15MB).
// MODES: 1: a1=tanh(hx@W1^T+b1); 2: gates=act(a1@W2^T+b2), act=sigm(tanh) for
// i2/f2, tanh(sigm(tanh)) for z. Both GB=12 (3 nets x 4 ny per mtile).
// LDS: 3 staging buffers (48KB) -> 3 blocks/CU; scratch reuses [0..16383].
// NOTE: never runtime-index acc[]/frag arrays (scratch spill lesson).
// ---------------------------------------------------------------------------
template <int MODE>
__global__ __launch_bounds__(256) void gemm_kernel(
    const __bf16* __restrict__ Ab,     // MODE1: hxb [M][512]; else a1 planes
    const __bf16* __restrict__ W,      // [3][512][512] bf16 (N,K) row-major
    const float* __restrict__ bias,    // [7][512] fp32
    __bf16* __restrict__ outb)         // MODE1: a1; MODE2: gates [3][M][512]
{
  // XCD-chunked bijective swizzle (grid.x = 1536, %8 == 0).
  const int bid = blockIdx.x;
  const int cpx = gridDim.x >> 3;                  // blocks per XCD chunk
  const int wg  = (bid & 7) * cpx + (bid >> 3);    // logical wg id
  const int mtile = wg / 12;                       // 12 wgs per mtile
  const int rem   = wg % 12;
  const int ny    = rem & 3;
  const int jj    = rem >> 2;                      // net index 0..2
  const int mbase = mtile * 128;
  const int nbase = ny * 128;
  constexpr size_t NH = (size_t)M * 512;

  const __bf16* Aj = (MODE == 1) ? Ab : Ab + (size_t)jj * NH;
  const __bf16* Wj = W + (size_t)jj * 262144;
  const int brow = 2 * jj + 1;                // bias row: i2=1, f2=3, z=5

  // 3 staging buffers x 8192 el (16KB each) = 48KB; scratch reuses [0..16383]
  __shared__ __align__(16) __bf16 smem[24576];

  const int tid  = threadIdx.x;
  const int wid  = tid >> 6;
  const int lane = tid & 63;
  const int wm   = (wid >> 1) * 64;
  const int wn   = (wid & 1) * 64;
  const int srow = wid * 16 + (lane >> 2);
  const int scol = ((lane & 3) ^ ((lane >> 3) & 3)) * 8;  // swizzled src chunk
  const int fr   = lane & 15;
  const int kc   = lane >> 4;
  const int sw   = (fr >> 1) & 3;
  const int rowq = kc * 4;

  auto stage = [&](int p, int k0) {
    __bf16* As = smem + p * 8192;
    __bf16* Bs = As + 4096;
#pragma unroll
    for (int r = 0; r < 2; ++r) {
      async_copy16(Aj + (size_t)(mbase + r * 64 + srow) * K + (k0 + scol),
                   (void*)&As[(r * 64 + wid * 16) * BK]);
      async_copy16(Wj + (size_t)(nbase + r * 64 + srow) * K + (k0 + scol),
                   (void*)&Bs[(r * 64 + wid * 16) * BK]);
    }
  };

  f32x4 acc[4][4] = {};

  stage(0, 0);
  stage(1, BK);
  int pr = 0, ps = 2;
  for (int t = 0; t < NT; ++t) {
    // ONE waitcnt: retire this wave's ds_reads (lgkmcnt 0) AND everything
    // but the newest stage (vmcnt 4) BEFORE the barrier. Tile t+2's copies
    // stay in flight across it (never drain to 0 mid-loop).
    if (t < NT - 2) asm volatile("s_waitcnt vmcnt(4) lgkmcnt(0)" ::: "memory");
    else            asm volatile("s_waitcnt vmcnt(0) lgkmcnt(0)" ::: "memory");
    __builtin_amdgcn_s_barrier();
    __builtin_amdgcn_sched_barrier(0);   // rule #18: pin code below the bar
    if (t < NT - 2) stage(ps, (t + 2) * BK);

    const __bf16* As = smem + pr * 8192;
    const __bf16* Bs = As + 4096;
    bf16x8 af[4], bfr[4];
#pragma unroll
    for (int i = 0; i < 4; ++i) {
      af[i]  = *(const bf16x8*)&As[(wm + i * 16 + fr) * BK + ((kc ^ sw) * 8)];
      bfr[i] = *(const bf16x8*)&Bs[(wn + i * 16 + fr) * BK + ((kc ^ sw) * 8)];
    }
#pragma unroll
    for (int mi = 0; mi < 4; ++mi)
#pragma unroll
      for (int ni = 0; ni < 4; ++ni)
        acc[mi][ni] = __builtin_amdgcn_mfma_f32_16x16x32_bf16(
            af[mi], bfr[ni], acc[mi][ni], 0, 0, 0);

    pr = (pr == 2) ? 0 : pr + 1;
    ps = (ps == 2) ? 0 : ps + 1;
  }

  // Epilogue. C/D layout: col=fr, row=rowq+r.
  float bv[4];
  const float* bj = bias + (size_t)brow * 512 + nbase + wn;
#pragma unroll
  for (int ni = 0; ni < 4; ++ni) bv[ni] = bj[ni * 16 + fr];

  __syncthreads();  // full drain once; smem reusable as C scratch
#pragma unroll
  for (int mi = 0; mi < 4; ++mi)
#pragma unroll
    for (int ni = 0; ni < 4; ++ni)
#pragma unroll
      for (int r = 0; r < 4; ++r) {
        float v = acc[mi][ni][r] + bv[ni];
        float res;
        if constexpr (MODE == 1) res = ftanh(v);
        else res = (jj == 2) ? ftanh(fsigm(ftanh(v)))   // z, stored tanh'd
                             : fsigm(ftanh(v));         // i2 / f2
        const int row = wm + mi * 16 + rowq + r;
        const int col = wn + ni * 16 + fr;
        smem[row * 128 + (col ^ kswz(row))] = (__bf16)res;
      }
  __syncthreads();
#pragma unroll
  for (int it = 0; it < 8; ++it) {
    const int s = it * 256 + tid;   // 0..2047
    const int row = s >> 4, ch = s & 15;
    bf16x8 v = *(const bf16x8*)&smem[row * 128 + ((ch * 8) ^ kswz(row))];
    *(bf16x8*)&outb[(size_t)jj * NH + (size_t)(mbase + row) * 512 +
                    (nbase + ch * 8)] = v;
  }
}

// cy2 = f2*cx2 + i2*z   gates = [i2 | f2 | z(tanh'd)] bf16 [3][M][512]
// (R0-proven streaming kernel)
__global__ __launch_bounds__(256) void final_kernel(
    const __bf16* __restrict__ gates, const float* __restrict__ cx2,
    float* __restrict__ out)
{
  constexpr size_t NH = (size_t)M * 512;
  const size_t i = ((size_t)blockIdx.x * 256 + threadIdx.x) * 8;
  bf16x8 i2 = *(const bf16x8*)&gates[i];
  bf16x8 f2 = *(const bf16x8*)&gates[NH + i];
  bf16x8 zz = *(const bf16x8*)&gates[2 * NH + i];
  f32x4 c0 = *(const f32x4*)&cx2[i];
  f32x4 c1 = *(const f32x4*)&cx2[i + 4];
#pragma unroll
  for (int h = 0; h < 2; ++h) {
    f32x4 r;
#pragma unroll
    for (int q = 0; q < 4; ++q) {
      const int e = h * 4 + q;
      r[q] = (float)f2[e] * (h ? c1[q] : c0[q]) + (float)i2[e] * (float)zz[e];
    }
    *(f32x4*)&out[i + h * 4] = r;
  }
}

// One conversion dispatch: blocks [0,1536) pick rows 2y+1 of W1/W2
// ([7][512][512] fp32) -> Wb [6][512][512] bf16; blocks [1536,9728) convert
// hx [M][512] fp32 -> hxb bf16.
__global__ __launch_bounds__(256) void cvt_all(const float* __restrict__ hx,
                                               const float* __restrict__ W1,
                                               const float* __restrict__ W2,
                                               __bf16* __restrict__ hxb,
                                               __bf16* __restrict__ Wb) {
  const int b = blockIdx.x;
  if (b < 1536) {
    const int y = b >> 8;          // 0..5
    const int bb = b & 255;
    const float* src = (y < 3) ? W1 + (size_t)(2 * y + 1) * 262144
                               : W2 + (size_t)(2 * (y - 3) + 1) * 262144;
    __bf16* d = Wb + (size_t)y * 262144;
    const size_t i = ((size_t)bb * 256 + threadIdx.x) * 4;
    f32x4 v = *(const f32x4*)&src[i];
    *(bf16x4*)&d[i] = __builtin_convertvector(v, bf16x4);
  } else {
    const size_t i = ((size_t)(b - 1536) * 256 + threadIdx.x) * 4;
    f32x4 v = *(const f32x4*)&hx[i];
    *(bf16x4*)&hxb[i] = __builtin_convertvector(v, bf16x4);
  }
}

extern "C" void kernel_launch(void* const* d_in, const int* in_sizes, int n_in,
                              void* d_out, int out_size, void* d_ws, size_t ws_size,
                              hipStream_t stream) {
  const float* hx  = (const float*)d_in[0];
  // d_in[1] = cx1 (dead: cy1 is never returned)
  const float* cx2 = (const float*)d_in[2];
  const float* W1  = (const float*)d_in[3];
  const float* b1  = (const float*)d_in[4];
  const float* W2  = (const float*)d_in[5];
  const float* b2  = (const float*)d_in[6];
  float* out = (float*)d_out;

  // ws: Wb @0 (3MB, [6] planes: 0-2=W1, 3-5=W2) | hxb @3MB (16MB) |
  //     a1 @19922944 (48MB) | gates @70254592 (48MB: i2,f2,z) -> ~118MB
  char* ws = (char*)d_ws;
  __bf16* Wb    = (__bf16*)(ws);
  __bf16* hxb   = (__bf16*)(ws + 3145728);
  __bf16* a1    = (__bf16*)(ws + 19922944);
  __bf16* gates = (__bf16*)(ws + 70254592);
  __bf16* W2b   = Wb + 3 * 262144;

  cvt_all<<<9728, 256, 0, stream>>>(hx, W1, W2, hxb, Wb);

  // layer 1 (3 nets): 1536 wgs = 128 mtiles x 12 -> exactly 2 full rounds
  gemm_kernel<1><<<1536, 256, 0, stream>>>(hxb, Wb, b1, a1);
  // layer 2 (3 nets incl z): 1536 wgs -> exactly 2 full rounds
  gemm_kernel<2><<<1536, 256, 0, stream>>>(a1, W2b, b2, gates);
  // combine (perfectly packed streaming)
  final_kernel<<<4096, 256, 0, stream>>>(gates, cx2, out);
}

// Round 11
// 218.932 us; speedup vs baseline: 1.2865x; 1.0162x over previous
//
#include <hip/hip_runtime.h>
#include <hip/hip_bf16.h>

typedef __attribute__((ext_vector_type(8))) __bf16 bf16x8;
typedef __attribute__((ext_vector_type(4))) __bf16 bf16x4;
typedef __attribute__((ext_vector_type(4))) float f32x4;

constexpr int M = 16384;
constexpr int K = 512;
constexpr int BK = 32;
constexpr int NT = 16;       // K / BK

__device__ __forceinline__ void async_copy16(const void* gsrc, void* ldst) {
  __builtin_amdgcn_global_load_lds(
      (const __attribute__((address_space(1))) unsigned int*)(gsrc),
      (__attribute__((address_space(3))) unsigned int*)(ldst),
      16, 0, 0);
}

__device__ __forceinline__ float frcp(float x) { return __builtin_amdgcn_rcpf(x); }
__device__ __forceinline__ float ftanh(float x) {
  return 1.0f - 2.0f * frcp(1.0f + __expf(2.0f * x));
}
__device__ __forceinline__ float fsigm(float x) { return frcp(1.0f + __expf(-x)); }

// Epilogue scratch swizzle (R4-proven): row stride 128 els (256B, bank-
// aligned); per-row XOR on the 8-el chunk gives the 4 kc row-groups distinct
// shifts -> stores 2-way max (free), reads cover each row once.
__device__ __forceinline__ int kswz(int row) {
  return ((row & 3) << 3) ^ ((row & 12) << 2);
}

// ---------------------------------------------------------------------------
// R11 = R10 (best known, 222.5us) + NON-TEMPORAL hints on all stream-once
// traffic. R10 POST-MORTEM: layer-2 GEMM runs 33us/round vs layer-1's 20.5
// with FETCH 37MB (a1 re-read largely MISSING L3): the bench iteration's
// working set (~226MB) ~ L3 capacity, and g2's own 48MB gate-write stream
// evicts un-staged a1 panels -> A-staging at HBM latency (~900cy) > the
// pipeline's 2-step lead. FIX (hints only, no functional change):
//   nt stores: g2 gates (read once by final, which runs at HBM rate anyway),
//              final out; nt loads: final gates/cx2, cvt_all fp32 sources.
//   NORMAL (protected, reused): a1 stores+reads, hxb/Wb everywhere.
// Removes ~112MB/iter of dead L2/L3 allocation -> a1 stays L3-resident.
// Established this session: 2-phase lockstep plateau (~500-630 TF) at this
// shape; counted-vmcnt / geometry / 4-phase-split all null or regress
// (R5-R8); XCD chunk swizzle real (FETCH 31->15MB, R9); uniform 1536-block
// packing best (R10).
// MODES: 1: a1=tanh(hx@W1^T+b1); 2: gates=act(a1@W2^T+b2), act=sigm(tanh)
// for i2/f2, tanh(sigm(tanh)) for z. Both GB=12 (3 nets x 4 ny per mtile).
// LDS: 3 staging buffers (48KB) -> 3 blocks/CU; scratch reuses [0..16383].
// NOTE: never runtime-index acc[]/frag arrays (scratch spill lesson).
// ---------------------------------------------------------------------------
template <int MODE>
__global__ __launch_bounds__(256) void gemm_kernel(
    const __bf16* __restrict__ Ab,     // MODE1: hxb [M][512]; else a1 planes
    const __bf16* __restrict__ W,      // [3][512][512] bf16 (N,K) row-major
    const float* __restrict__ bias,    // [7][512] fp32
    __bf16* __restrict__ outb)         // MODE1: a1; MODE2: gates [3][M][512]
{
  // XCD-chunked bijective swizzle (grid.x = 1536, %8 == 0).
  const int bid = blockIdx.x;
  const int cpx = gridDim.x >> 3;                  // blocks per XCD chunk
  const int wg  = (bid & 7) * cpx + (bid >> 3);    // logical wg id
  const int mtile = wg / 12;                       // 12 wgs per mtile
  const int rem   = wg % 12;
  const int ny    = rem & 3;
  const int jj    = rem >> 2;                      // net index 0..2
  const int mbase = mtile * 128;
  const int nbase = ny * 128;
  constexpr size_t NH = (size_t)M * 512;

  const __bf16* Aj = (MODE == 1) ? Ab : Ab + (size_t)jj * NH;
  const __bf16* Wj = W + (size_t)jj * 262144;
  const int brow = 2 * jj + 1;                // bias row: i2=1, f2=3, z=5

  // 3 staging buffers x 8192 el (16KB each) = 48KB; scratch reuses [0..16383]
  __shared__ __align__(16) __bf16 smem[24576];

  const int tid  = threadIdx.x;
  const int wid  = tid >> 6;
  const int lane = tid & 63;
  const int wm   = (wid >> 1) * 64;
  const int wn   = (wid & 1) * 64;
  const int srow = wid * 16 + (lane >> 2);
  const int scol = ((lane & 3) ^ ((lane >> 3) & 3)) * 8;  // swizzled src chunk
  const int fr   = lane & 15;
  const int kc   = lane >> 4;
  const int sw   = (fr >> 1) & 3;
  const int rowq = kc * 4;

  auto stage = [&](int p, int k0) {
    __bf16* As = smem + p * 8192;
    __bf16* Bs = As + 4096;
#pragma unroll
    for (int r = 0; r < 2; ++r) {
      async_copy16(Aj + (size_t)(mbase + r * 64 + srow) * K + (k0 + scol),
                   (void*)&As[(r * 64 + wid * 16) * BK]);
      async_copy16(Wj + (size_t)(nbase + r * 64 + srow) * K + (k0 + scol),
                   (void*)&Bs[(r * 64 + wid * 16) * BK]);
    }
  };

  f32x4 acc[4][4] = {};

  stage(0, 0);
  stage(1, BK);
  int pr = 0, ps = 2;
  for (int t = 0; t < NT; ++t) {
    // ONE waitcnt: retire this wave's ds_reads (lgkmcnt 0) AND everything
    // but the newest stage (vmcnt 4) BEFORE the barrier. Tile t+2's copies
    // stay in flight across it (never drain to 0 mid-loop).
    if (t < NT - 2) asm volatile("s_waitcnt vmcnt(4) lgkmcnt(0)" ::: "memory");
    else            asm volatile("s_waitcnt vmcnt(0) lgkmcnt(0)" ::: "memory");
    __builtin_amdgcn_s_barrier();
    __builtin_amdgcn_sched_barrier(0);   // rule #18: pin code below the bar
    if (t < NT - 2) stage(ps, (t + 2) * BK);

    const __bf16* As = smem + pr * 8192;
    const __bf16* Bs = As + 4096;
    bf16x8 af[4], bfr[4];
#pragma unroll
    for (int i = 0; i < 4; ++i) {
      af[i]  = *(const bf16x8*)&As[(wm + i * 16 + fr) * BK + ((kc ^ sw) * 8)];
      bfr[i] = *(const bf16x8*)&Bs[(wn + i * 16 + fr) * BK + ((kc ^ sw) * 8)];
    }
#pragma unroll
    for (int mi = 0; mi < 4; ++mi)
#pragma unroll
      for (int ni = 0; ni < 4; ++ni)
        acc[mi][ni] = __builtin_amdgcn_mfma_f32_16x16x32_bf16(
            af[mi], bfr[ni], acc[mi][ni], 0, 0, 0);

    pr = (pr == 2) ? 0 : pr + 1;
    ps = (ps == 2) ? 0 : ps + 1;
  }

  // Epilogue. C/D layout: col=fr, row=rowq+r.
  float bv[4];
  const float* bj = bias + (size_t)brow * 512 + nbase + wn;
#pragma unroll
  for (int ni = 0; ni < 4; ++ni) bv[ni] = bj[ni * 16 + fr];

  __syncthreads();  // full drain once; smem reusable as C scratch
#pragma unroll
  for (int mi = 0; mi < 4; ++mi)
#pragma unroll
    for (int ni = 0; ni < 4; ++ni)
#pragma unroll
      for (int r = 0; r < 4; ++r) {
        float v = acc[mi][ni][r] + bv[ni];
        float res;
        if constexpr (MODE == 1) res = ftanh(v);
        else res = (jj == 2) ? ftanh(fsigm(ftanh(v)))   // z, stored tanh'd
                             : fsigm(ftanh(v));         // i2 / f2
        const int row = wm + mi * 16 + rowq + r;
        const int col = wn + ni * 16 + fr;
        smem[row * 128 + (col ^ kswz(row))] = (__bf16)res;
      }
  __syncthreads();
#pragma unroll
  for (int it = 0; it < 8; ++it) {
    const int s = it * 256 + tid;   // 0..2047
    const int row = s >> 4, ch = s & 15;
    bf16x8 v = *(const bf16x8*)&smem[row * 128 + ((ch * 8) ^ kswz(row))];
    bf16x8* dst = (bf16x8*)&outb[(size_t)jj * NH + (size_t)(mbase + row) * 512 +
                                 (nbase + ch * 8)];
    if constexpr (MODE == 2)
      __builtin_nontemporal_store(v, dst);  // gates: stream-once, protect L3
    else
      *dst = v;                             // a1: KEEP cached (reused by g2)
  }
}

// cy2 = f2*cx2 + i2*z   gates = [i2 | f2 | z(tanh'd)] bf16 [3][M][512]
// (R0-proven streaming kernel; all traffic stream-once -> fully nt)
__global__ __launch_bounds__(256) void final_kernel(
    const __bf16* __restrict__ gates, const float* __restrict__ cx2,
    float* __restrict__ out)
{
  constexpr size_t NH = (size_t)M * 512;
  const size_t i = ((size_t)blockIdx.x * 256 + threadIdx.x) * 8;
  bf16x8 i2 = __builtin_nontemporal_load((const bf16x8*)&gates[i]);
  bf16x8 f2 = __builtin_nontemporal_load((const bf16x8*)&gates[NH + i]);
  bf16x8 zz = __builtin_nontemporal_load((const bf16x8*)&gates[2 * NH + i]);
  f32x4 c0 = __builtin_nontemporal_load((const f32x4*)&cx2[i]);
  f32x4 c1 = __builtin_nontemporal_load((const f32x4*)&cx2[i + 4]);
#pragma unroll
  for (int h = 0; h < 2; ++h) {
    f32x4 r;
#pragma unroll
    for (int q = 0; q < 4; ++q) {
      const int e = h * 4 + q;
      r[q] = (float)f2[e] * (h ? c1[q] : c0[q]) + (float)i2[e] * (float)zz[e];
    }
    __builtin_nontemporal_store(r, (f32x4*)&out[i + h * 4]);
  }
}

// One conversion dispatch: blocks [0,1536) pick rows 2y+1 of W1/W2
// ([7][512][512] fp32) -> Wb [6][512][512] bf16; blocks [1536,9728) convert
// hx [M][512] fp32 -> hxb bf16. fp32 sources are read-once -> nt loads;
// bf16 outputs are re-read by the GEMMs -> normal stores.
__global__ __launch_bounds__(256) void cvt_all(const float* __restrict__ hx,
                                               const float* __restrict__ W1,
                                               const float* __restrict__ W2,
                                               __bf16* __restrict__ hxb,
                                               __bf16* __restrict__ Wb) {
  const int b = blockIdx.x;
  if (b < 1536) {
    const int y = b >> 8;          // 0..5
    const int bb = b & 255;
    const float* src = (y < 3) ? W1 + (size_t)(2 * y + 1) * 262144
                               : W2 + (size_t)(2 * (y - 3) + 1) * 262144;
    __bf16* d = Wb + (size_t)y * 262144;
    const size_t i = ((size_t)bb * 256 + threadIdx.x) * 4;
    f32x4 v = __builtin_nontemporal_load((const f32x4*)&src[i]);
    *(bf16x4*)&d[i] = __builtin_convertvector(v, bf16x4);
  } else {
    const size_t i = ((size_t)(b - 1536) * 256 + threadIdx.x) * 4;
    f32x4 v = __builtin_nontemporal_load((const f32x4*)&hx[i]);
    *(bf16x4*)&hxb[i] = __builtin_convertvector(v, bf16x4);
  }
}

extern "C" void kernel_launch(void* const* d_in, const int* in_sizes, int n_in,
                              void* d_out, int out_size, void* d_ws, size_t ws_size,
                              hipStream_t stream) {
  const float* hx  = (const float*)d_in[0];
  // d_in[1] = cx1 (dead: cy1 is never returned)
  const float* cx2 = (const float*)d_in[2];
  const float* W1  = (const float*)d_in[3];
  const float* b1  = (const float*)d_in[4];
  const float* W2  = (const float*)d_in[5];
  const float* b2  = (const float*)d_in[6];
  float* out = (float*)d_out;

  // ws: Wb @0 (3MB, [6] planes: 0-2=W1, 3-5=W2) | hxb @3MB (16MB) |
  //     a1 @19922944 (48MB) | gates @70254592 (48MB: i2,f2,z) -> ~118MB
  char* ws = (char*)d_ws;
  __bf16* Wb    = (__bf16*)(ws);
  __bf16* hxb   = (__bf16*)(ws + 3145728);
  __bf16* a1    = (__bf16*)(ws + 19922944);
  __bf16* gates = (__bf16*)(ws + 70254592);
  __bf16* W2b   = Wb + 3 * 262144;

  cvt_all<<<9728, 256, 0, stream>>>(hx, W1, W2, hxb, Wb);

  // layer 1 (3 nets): 1536 wgs = 128 mtiles x 12 -> exactly 2 full rounds
  gemm_kernel<1><<<1536, 256, 0, stream>>>(hxb, Wb, b1, a1);
  // layer 2 (3 nets incl z): 1536 wgs -> exactly 2 full rounds
  gemm_kernel<2><<<1536, 256, 0, stream>>>(a1, W2b, b2, gates);
  // combine (perfectly packed streaming, fully nt)
  final_kernel<<<4096, 256, 0, stream>>>(gates, cx2, out);
}